// Round 5
// baseline (790.243 us; speedup 1.0000x reference)
//
#include <hip/hip_runtime.h>

#define N_OUT   128
#define IN_DIM  128
#define EDGE_D  16
#define TILE    128
#define TILE_N  64
#define NKG_E   18    // edge kgroups of 8 k (144 exact, no pad)
#define NKG_N   32    // node kgroups (256 k)
#define SM_S    132   // sM row stride in floats (conflict-free)

typedef short  s16x8 __attribute__((ext_vector_type(8)));
typedef float  f32x4 __attribute__((ext_vector_type(4)));

__device__ __forceinline__ ushort f2bf(float f) {
    unsigned u = __float_as_uint(f);
    return (ushort)((u + 0x7FFFu + ((u >> 16) & 1u)) >> 16);   // RNE
}
__device__ __forceinline__ float bf2f(ushort h) {
    return __uint_as_float(((unsigned)h) << 16);
}

// ---------------- one-time prep ----------------
__global__ void split_kernel(const float* __restrict__ x, ushort* __restrict__ xh,
                             ushort* __restrict__ xl, int n) {
    int i = blockIdx.x * blockDim.x + threadIdx.x;
    if (i < n) {
        float f = x[i];
        ushort h = f2bf(f);
        xh[i] = h;
        xl[i] = f2bf(f - bf2f(h));
    }
}

// W [K][128] f32 -> hi/lo bf16 in MFMA B-frag layout: [(k/8)*128 + col]*8 + (k&7)
__global__ void wprep_kernel(const float* __restrict__ W, ushort* __restrict__ Whf,
                             ushort* __restrict__ Wlf, int K) {
    int i = blockIdx.x * blockDim.x + threadIdx.x;
    if (i >= K * N_OUT) return;
    int k = i >> 7, col = i & 127;
    float f = W[k * N_OUT + col];
    ushort h = f2bf(f);
    int d = ((k >> 3) * N_OUT + col) * 8 + (k & 7);
    Whf[d] = h;
    Wlf[d] = f2bf(f - bf2f(h));
}

// ---------------- CSR build (once; src/dst are layer-invariant) ----------------
__global__ void hist_kernel(const int* __restrict__ dst, int* __restrict__ hist, int nE) {
    int e = blockIdx.x * blockDim.x + threadIdx.x;
    if (e < nE) atomicAdd(&hist[dst[e]], 1);
}

__global__ void scan_kernel(const int* __restrict__ hist, int* __restrict__ rowptr, int n) {
    __shared__ int buf[1024];
    __shared__ int carry;
    if (threadIdx.x == 0) carry = 0;
    __syncthreads();
    int nch = (n + 1023) >> 10;
    for (int ch = 0; ch < nch; ++ch) {
        int i = (ch << 10) + threadIdx.x;
        int v = (i < n) ? hist[i] : 0;
        buf[threadIdx.x] = v;
        __syncthreads();
        for (int off = 1; off < 1024; off <<= 1) {
            int t = (threadIdx.x >= (unsigned)off) ? buf[threadIdx.x - off] : 0;
            __syncthreads();
            buf[threadIdx.x] += t;
            __syncthreads();
        }
        if (i < n) rowptr[i] = carry + buf[threadIdx.x] - v;   // exclusive
        __syncthreads();
        if (threadIdx.x == 1023) carry += buf[1023];
        __syncthreads();
    }
}

__global__ void scatter_kernel(const int* __restrict__ src, const int* __restrict__ dst,
                               const int* __restrict__ rowptr, int* __restrict__ cursor,
                               int* __restrict__ eperm, int* __restrict__ srcS,
                               int* __restrict__ dstS, int nE) {
    int e = blockIdx.x * blockDim.x + threadIdx.x;
    if (e < nE) {
        int d = dst[e];
        int pos = rowptr[d] + atomicAdd(&cursor[d], 1);
        eperm[pos] = e;
        dstS[pos]  = d;
        srcS[pos]  = src[e];
    }
}

__global__ void deg_kernel(const int* __restrict__ hist, float* __restrict__ cntf, int n) {
    int i = blockIdx.x * blockDim.x + threadIdx.x;
    if (i < n) cntf[i] = (float)hist[i];
}

// ---------------- edge GEMM (split-bf16 MFMA, pipelined) + segment-reduce ----------------
// 2 blocks/CU: LDS 74.2KB (sM aliased over sA; KPAD=144, pad k handled by zero frags).
__global__ __launch_bounds__(512, 2) void edge_mfma_kernel(
    const ushort* __restrict__ xh, const ushort* __restrict__ xl,
    const int*   __restrict__ srcS,
    const int*   __restrict__ eperm,
    const int*   __restrict__ dstS,
    const float* __restrict__ ea,
    const ushort* __restrict__ Whf,
    const ushort* __restrict__ Wlf,
    const float* __restrict__ bias,
    float* __restrict__ agg,     // pre-zeroed
    int nE, int nTiles)
{
    // manual carve so sM can alias sA (phase-disjoint)
    __shared__ __align__(16) char smem[NKG_E*TILE*16*2 + TILE*4];   // 74240 B
    ushort* sAh  = (ushort*)smem;                       // 36864 B
    ushort* sAl  = (ushort*)(smem + NKG_E*TILE*16);     // 36864 B
    int*    sDst = (int*)(smem + NKG_E*TILE*16*2);      // 512 B
    float*  sM   = (float*)smem;                        // 67584 B, aliases sAh+sAl

    const int tid  = threadIdx.x;
    const int w    = tid >> 6;
    const int lane = tid & 63;
    const int lg   = lane >> 4;
    const int lr   = lane & 15;
    const int col  = w * 16 + lr;
    const s16x8 z8 = {0,0,0,0,0,0,0,0};

    // B fragments; kb=4 covers k128..159 but only kg16,17 (k128..143) exist
    s16x8 Bh[5], Bl[5];
    #pragma unroll
    for (int kb = 0; kb < 5; ++kb) {
        int kg = kb * 4 + lg;
        if (kg < NKG_E) {
            Bh[kb] = *(const s16x8*)&Whf[(kg * N_OUT + col) * 8];
            Bl[kb] = *(const s16x8*)&Wlf[(kg * N_OUT + col) * 8];
        } else {
            Bh[kb] = z8;
            Bl[kb] = z8;
        }
    }
    const float bv = bias[col];

    const int row = tid & 127;   // tile row this thread stages
    const int c   = tid >> 7;    // k-quarter (32 k) of the x part

    s16x8 rh[4], rl[4];
    float4 re4[4];
    int rdst = 0x7fffffff;

    auto prefetch = [&](int tile) {
        int p = tile * TILE + row;
        bool valid = (p < nE);
        int s = valid ? srcS[p] : 0;
        const s16x8* ph = (const s16x8*)(xh + (size_t)s * IN_DIM + c * 32);
        const s16x8* pl = (const s16x8*)(xl + (size_t)s * IN_DIM + c * 32);
        #pragma unroll
        for (int g = 0; g < 4; ++g) { rh[g] = ph[g]; rl[g] = pl[g]; }
        if (c == 0) {
            int e = valid ? eperm[p] : 0;
            const float4* pe = (const float4*)(ea + (size_t)e * EDGE_D);
            #pragma unroll
            for (int g = 0; g < 4; ++g) re4[g] = pe[g];
            rdst = valid ? dstS[p] : 0x7fffffff;
        }
    };

    prefetch(blockIdx.x);

    for (int tile = blockIdx.x; tile < nTiles; tile += gridDim.x) {
        __syncthreads();   // prev reduce's sM reads done (sM aliases sA)
        #pragma unroll
        for (int g = 0; g < 4; ++g) {
            *(s16x8*)&sAh[((c*4 + g) * TILE + row) * 8] = rh[g];
            *(s16x8*)&sAl[((c*4 + g) * TILE + row) * 8] = rl[g];
        }
        if (c == 0) {   // edge_attr: convert 16 f32 -> hi/lo (kgroups 16,17)
            float a[16] = {re4[0].x, re4[0].y, re4[0].z, re4[0].w,
                           re4[1].x, re4[1].y, re4[1].z, re4[1].w,
                           re4[2].x, re4[2].y, re4[2].z, re4[2].w,
                           re4[3].x, re4[3].y, re4[3].z, re4[3].w};
            #pragma unroll
            for (int g = 0; g < 2; ++g) {
                s16x8 hv, lv;
                #pragma unroll
                for (int j = 0; j < 8; ++j) {
                    float f = a[g*8 + j];
                    ushort h = f2bf(f);
                    hv[j] = (short)h;
                    lv[j] = (short)f2bf(f - bf2f(h));
                }
                *(s16x8*)&sAh[((16 + g) * TILE + row) * 8] = hv;
                *(s16x8*)&sAl[((16 + g) * TILE + row) * 8] = lv;
            }
            sDst[row] = rdst;
        }
        __syncthreads();   // A-tile visible

        prefetch(tile + gridDim.x);   // global loads overlap MFMA + reduce

        f32x4 acc[8];
        #pragma unroll
        for (int b = 0; b < 8; ++b) acc[b] = (f32x4){bv, bv, bv, bv};

        #pragma unroll
        for (int kb = 0; kb < 4; ++kb) {
            #pragma unroll
            for (int b = 0; b < 8; ++b) {
                const int base = ((kb*4 + lg) * TILE + b*16 + lr) * 8;
                s16x8 ah = *(const s16x8*)&sAh[base];
                s16x8 al = *(const s16x8*)&sAl[base];
                acc[b] = __builtin_amdgcn_mfma_f32_16x16x32_bf16(ah, Bh[kb], acc[b], 0, 0, 0);
                acc[b] = __builtin_amdgcn_mfma_f32_16x16x32_bf16(al, Bh[kb], acc[b], 0, 0, 0);
                acc[b] = __builtin_amdgcn_mfma_f32_16x16x32_bf16(ah, Bl[kb], acc[b], 0, 0, 0);
            }
        }
        {   // kb = 4: lg<2 -> kg 16/17; lg>=2 -> zero frags (k144..159 don't exist)
            #pragma unroll
            for (int b = 0; b < 8; ++b) {
                const int base = ((16 + (lg & 1)) * TILE + b*16 + lr) * 8;
                s16x8 ah = *(const s16x8*)&sAh[base];
                s16x8 al = *(const s16x8*)&sAl[base];
                if (lg >= 2) { ah = z8; al = z8; }
                acc[b] = __builtin_amdgcn_mfma_f32_16x16x32_bf16(ah, Bh[4], acc[b], 0, 0, 0);
                acc[b] = __builtin_amdgcn_mfma_f32_16x16x32_bf16(al, Bh[4], acc[b], 0, 0, 0);
                acc[b] = __builtin_amdgcn_mfma_f32_16x16x32_bf16(ah, Bl[4], acc[b], 0, 0, 0);
            }
        }
        __syncthreads();   // all MFMA reads of sA done before sM overwrites it

        #pragma unroll
        for (int b = 0; b < 8; ++b) {
            #pragma unroll
            for (int r = 0; r < 4; ++r) {
                sM[(b*16 + lg*4 + r) * SM_S + col] = fmaxf(acc[b][r], 0.0f);
            }
        }
        __syncthreads();   // sM visible

        // segment reduce over sorted dst, one atomic per (segment-chunk, col)
        {
            const int ne   = min(TILE, nE - tile * TILE);
            const int colr = tid & 127;
            const int q    = tid >> 7;
            const int rb   = q * 32;
            const int rend = min(rb + 32, ne);
            if (rb < ne) {
                int dprev = sDst[rb];
                float sum = sM[rb * SM_S + colr];
                for (int r = rb + 1; r < rend; ++r) {
                    int d = sDst[r];
                    float v = sM[r * SM_S + colr];
                    if (d == dprev) sum += v;
                    else {
                        atomicAdd(&agg[(size_t)dprev * N_OUT + colr], sum);
                        dprev = d; sum = v;
                    }
                }
                atomicAdd(&agg[(size_t)dprev * N_OUT + colr], sum);
            }
        }
    }
}

// ---------------- node update (split-bf16 MFMA): relu(concat(h, agg/cnt) @ U) ----------------
// TILE_N=64 rows -> 64KB LDS -> 2 blocks/CU.
__global__ __launch_bounds__(512, 2) void node_mfma_kernel(
    const ushort* __restrict__ hh, const ushort* __restrict__ hl,
    const float* __restrict__ agg, const float* __restrict__ cnt,
    const ushort* __restrict__ Uhf, const ushort* __restrict__ Ulf,
    float* __restrict__ outf, ushort* __restrict__ outh, ushort* __restrict__ outl,
    int lastLayer, int nNodes, int nTiles)
{
    __shared__ ushort sAh[NKG_N * TILE_N * 8];   // 32768 B
    __shared__ ushort sAl[NKG_N * TILE_N * 8];   // 32768 B

    const int tid  = threadIdx.x;
    const int w    = tid >> 6;
    const int lane = tid & 63;
    const int lg   = lane >> 4;
    const int lr   = lane & 15;
    const int col  = w * 16 + lr;

    s16x8 Bh[8], Bl[8];
    #pragma unroll
    for (int kb = 0; kb < 8; ++kb) {
        int kg = kb * 4 + lg;
        Bh[kb] = *(const s16x8*)&Uhf[(kg * N_OUT + col) * 8];
        Bl[kb] = *(const s16x8*)&Ulf[(kg * N_OUT + col) * 8];
    }

    const int row = tid & 63;    // tile row this thread stages
    const int c   = tid >> 6;    // k-eighth (32 k)

    for (int tile = blockIdx.x; tile < nTiles; tile += gridDim.x) {
        __syncthreads();
        const int i = tile * TILE_N + row;
        const bool valid = (i < nNodes);
        const int ii = valid ? i : 0;
        if (c < 4) {   // h part: kgroups c*4 .. c*4+3 (direct bf16 copy)
            const s16x8* ph = (const s16x8*)(hh + (size_t)ii * N_OUT + c * 32);
            const s16x8* pl = (const s16x8*)(hl + (size_t)ii * N_OUT + c * 32);
            #pragma unroll
            for (int g = 0; g < 4; ++g) {
                *(s16x8*)&sAh[((c*4 + g) * TILE_N + row) * 8] = ph[g];
                *(s16x8*)&sAl[((c*4 + g) * TILE_N + row) * 8] = pl[g];
            }
        } else {       // agg part: scale by 1/deg, split
            float rc = 1.0f / fmaxf(cnt[ii], 1.0f);
            const float4* pa = (const float4*)(agg + (size_t)ii * N_OUT + (c - 4) * 32);
            #pragma unroll
            for (int g = 0; g < 4; ++g) {
                float4 v0 = pa[g*2], v1 = pa[g*2 + 1];
                float a[8] = {v0.x, v0.y, v0.z, v0.w, v1.x, v1.y, v1.z, v1.w};
                s16x8 hv, lv;
                #pragma unroll
                for (int j = 0; j < 8; ++j) {
                    float f = a[j] * rc;
                    ushort h = f2bf(f);
                    hv[j] = (short)h;
                    lv[j] = (short)f2bf(f - bf2f(h));
                }
                int kg = 16 + (c - 4) * 4 + g;
                *(s16x8*)&sAh[(kg * TILE_N + row) * 8] = hv;
                *(s16x8*)&sAl[(kg * TILE_N + row) * 8] = lv;
            }
        }
        __syncthreads();

        f32x4 acc[4];
        #pragma unroll
        for (int b = 0; b < 4; ++b) acc[b] = (f32x4){0.f, 0.f, 0.f, 0.f};

        #pragma unroll
        for (int kb = 0; kb < 8; ++kb) {
            #pragma unroll
            for (int b = 0; b < 4; ++b) {
                const int base = ((kb*4 + lg) * TILE_N + b*16 + lr) * 8;
                s16x8 ah = *(const s16x8*)&sAh[base];
                s16x8 al = *(const s16x8*)&sAl[base];
                acc[b] = __builtin_amdgcn_mfma_f32_16x16x32_bf16(ah, Bh[kb], acc[b], 0, 0, 0);
                acc[b] = __builtin_amdgcn_mfma_f32_16x16x32_bf16(al, Bh[kb], acc[b], 0, 0, 0);
                acc[b] = __builtin_amdgcn_mfma_f32_16x16x32_bf16(ah, Bl[kb], acc[b], 0, 0, 0);
            }
        }

        #pragma unroll
        for (int b = 0; b < 4; ++b) {
            #pragma unroll
            for (int r = 0; r < 4; ++r) {
                int rr = tile * TILE_N + b*16 + lg*4 + r;
                if (rr < nNodes) {
                    float v = fmaxf(acc[b][r], 0.0f);
                    if (lastLayer) {
                        outf[(size_t)rr * N_OUT + col] = v;
                    } else {
                        ushort h = f2bf(v);
                        outh[(size_t)rr * N_OUT + col] = h;
                        outl[(size_t)rr * N_OUT + col] = f2bf(v - bf2f(h));
                    }
                }
            }
        }
    }
}

extern "C" void kernel_launch(void* const* d_in, const int* in_sizes, int n_in,
                              void* d_out, int out_size, void* d_ws, size_t ws_size,
                              hipStream_t stream)
{
    const float* x  = (const float*)d_in[0];
    const int*   ei = (const int*)  d_in[1];
    const float* ea = (const float*)d_in[2];
    const float* W1 = (const float*)d_in[3];
    const float* b1 = (const float*)d_in[4];
    const float* U1 = (const float*)d_in[5];
    const float* W2 = (const float*)d_in[6];
    const float* b2 = (const float*)d_in[7];
    const float* U2 = (const float*)d_in[8];

    const int nE      = in_sizes[1] / 2;
    const int nNodes  = in_sizes[0] / IN_DIM;
    const int nTilesE = (nE + TILE - 1) / TILE;
    const int nTilesN = (nNodes + TILE_N - 1) / TILE_N;
    const int* srcp = ei;
    const int* dstp = ei + nE;

    char* p = (char*)d_ws;
    auto alloc = [&](size_t bytes) { void* r = (void*)p; p += (bytes + 255) & ~(size_t)255; return r; };

    float*  agg   = (float*) alloc((size_t)nNodes * N_OUT * sizeof(float));
    ushort* xhh   = (ushort*)alloc((size_t)nNodes * N_OUT * sizeof(ushort));
    ushort* xll   = (ushort*)alloc((size_t)nNodes * N_OUT * sizeof(ushort));
    float*  cntf  = (float*) alloc((size_t)nNodes * sizeof(float));
    int*    hist  = (int*)   alloc((size_t)nNodes * sizeof(int));
    int*    rowptr= (int*)   alloc((size_t)(nNodes + 1) * sizeof(int));
    int*    cursor= (int*)   alloc((size_t)nNodes * sizeof(int));
    int*    eperm = (int*)   alloc((size_t)nE * sizeof(int));
    int*    dstS  = (int*)   alloc((size_t)nE * sizeof(int));
    int*    srcS  = (int*)   alloc((size_t)nE * sizeof(int));
    ushort* Whf1  = (ushort*)alloc((size_t)NKG_E * 8 * N_OUT * sizeof(ushort));
    ushort* Wlf1  = (ushort*)alloc((size_t)NKG_E * 8 * N_OUT * sizeof(ushort));
    ushort* Whf2  = (ushort*)alloc((size_t)NKG_E * 8 * N_OUT * sizeof(ushort));
    ushort* Wlf2  = (ushort*)alloc((size_t)NKG_E * 8 * N_OUT * sizeof(ushort));
    ushort* Uhf1  = (ushort*)alloc((size_t)NKG_N * 8 * N_OUT * sizeof(ushort));
    ushort* Ulf1  = (ushort*)alloc((size_t)NKG_N * 8 * N_OUT * sizeof(ushort));
    ushort* Uhf2  = (ushort*)alloc((size_t)NKG_N * 8 * N_OUT * sizeof(ushort));
    ushort* Ulf2  = (ushort*)alloc((size_t)NKG_N * 8 * N_OUT * sizeof(ushort));
    float*  outp  = (float*)d_out;

    // ---- one-time prep: CSR, degree, weight frags, x split ----
    hipMemsetAsync(hist,   0, (size_t)nNodes * sizeof(int), stream);
    hipMemsetAsync(cursor, 0, (size_t)nNodes * sizeof(int), stream);
    hist_kernel<<<(nE + 255)/256, 256, 0, stream>>>(dstp, hist, nE);
    scan_kernel<<<1, 1024, 0, stream>>>(hist, rowptr, nNodes);
    scatter_kernel<<<(nE + 255)/256, 256, 0, stream>>>(srcp, dstp, rowptr, cursor,
                                                       eperm, srcS, dstS, nE);
    deg_kernel<<<(nNodes + 255)/256, 256, 0, stream>>>(hist, cntf, nNodes);
    wprep_kernel<<<(NKG_E*8*N_OUT + 255)/256, 256, 0, stream>>>(W1, Whf1, Wlf1, NKG_E*8);
    wprep_kernel<<<(NKG_E*8*N_OUT + 255)/256, 256, 0, stream>>>(W2, Whf2, Wlf2, NKG_E*8);
    wprep_kernel<<<(NKG_N*8*N_OUT + 255)/256, 256, 0, stream>>>(U1, Uhf1, Ulf1, NKG_N*8);
    wprep_kernel<<<(NKG_N*8*N_OUT + 255)/256, 256, 0, stream>>>(U2, Uhf2, Ulf2, NKG_N*8);
    split_kernel<<<((nNodes*N_OUT) + 255)/256, 256, 0, stream>>>(x, xhh, xll, nNodes * IN_DIM);

    auto run_layer = [&](const ushort* Whf, const ushort* Wlf, const float* b,
                         const ushort* Uhf, const ushort* Ulf, int last) {
        hipMemsetAsync(agg, 0, (size_t)nNodes * N_OUT * sizeof(float), stream);
        edge_mfma_kernel<<<512, 512, 0, stream>>>(xhh, xll, srcS, eperm, dstS, ea,
                                                  Whf, Wlf, b, agg, nE, nTilesE);
        node_mfma_kernel<<<512, 512, 0, stream>>>(xhh, xll, agg, cntf, Uhf, Ulf,
                                                  outp, xhh, xll, last, nNodes, nTilesN);
    };

    run_layer(Whf1, Wlf1, b1, Uhf1, Ulf1, 0);   // conv1 -> (xhh,xll)
    run_layer(Whf2, Wlf2, b2, Uhf2, Ulf2, 0);   // conv2 -> (xhh,xll)
    run_layer(Whf2, Wlf2, b2, Uhf2, Ulf2, 1);   // conv3 -> d_out (f32)
}